// Round 1
// baseline (411.927 us; speedup 1.0000x reference)
//
#include <hip/hip_runtime.h>
#include <float.h>

#define HEADS 8
#define DIM 64
#define BATCH 2
#define SEQ 2048
#define KNN 32
#define QT 64
#define NEGF (-3.402823466e38f)

union F4 { float4 v; float f[4]; };

// ws layout: [0..4): int flag (1 = mem_mask is int32, 0 = 1-byte bool); knT at byte 64: (B, D, S) fp32
__global__ __launch_bounds__(256) void prep_kernel(const float* __restrict__ k,
                                                   const unsigned char* __restrict__ mmraw,
                                                   float* __restrict__ knT,
                                                   int* __restrict__ flag) {
    int w = threadIdx.x >> 6, lane = threadIdx.x & 63;
    int row = blockIdx.x * 4 + w;               // b*SEQ + s
    int b = row >> 11, s = row & 2047;
    float val = k[(size_t)row * DIM + lane];
    float ssq = val * val;
    #pragma unroll
    for (int m = 1; m < 64; m <<= 1) ssq += __shfl_xor(ssq, m);
    float kn = val / fmaxf(sqrtf(ssq), 1e-12f);
    knT[((size_t)b * DIM + lane) * SEQ + s] = kn;
    if (blockIdx.x == 0 && w == 0) {
        int bad = 0;
        #pragma unroll
        for (int t = 0; t < 8; t++) {
            int idx = t * 64 + lane;
            if ((idx & 3) != 0 && mmraw[idx] != 0) bad = 1;
        }
        unsigned long long anybad = __ballot(bad);
        if (lane == 0) flag[0] = (anybad == 0ULL) ? 1 : 0;
    }
}

__global__ __launch_bounds__(256) void attn_kernel(
    const float* __restrict__ q,          // B,H,S,D
    const float* __restrict__ v,          // B,S,D
    const float* __restrict__ scale_param,// H
    const float* __restrict__ mem_kv,     // B,H,S,KNN,2,D
    const float* __restrict__ mask,       // B,S (float)
    const void*  __restrict__ mem_mask,   // B,H,S,KNN (int32 or u8, see flag)
    const float* __restrict__ knTg,       // B,D,S (normalized k, transposed)
    const int*   __restrict__ flagp,
    float* __restrict__ out)              // B,H,S,D
{
    __shared__ float qnT[DIM][QT];        // [d][local row] 16 KB
    __shared__ float knT_s[DIM][QT + 4];  // [k][local col] padded, 17 KB
    __shared__ float maccs[QT][DIM];      // mem-branch acc, 16 KB
    __shared__ float ptile[4][16][36];    // per-wave P half-tile transpose, 9 KB
    __shared__ float pmem[4][KNN];        // per-wave mem p staging
    __shared__ float mmem_s[QT];
    __shared__ float lmem_s[QT];

    const int tid = threadIdx.x;
    const int w = tid >> 6;
    const int lane = tid & 63;
    const int bid = blockIdx.x;
    const int qt = 31 - (bid & 31);       // big tiles dispatched first
    const int bh = bid >> 5;              // b*H + h
    const int b = bh >> 3;
    const int h = bh & 7;
    const int i0 = qt * QT;

    const float scale = expf(scale_param[h]);
    const int mask_is_int = flagp[0];

    // ---------- Phase A: q-load+norm, mem branch (per wave, 16 rows) ----------
    {
        const int jm = lane & 31;
        const int half = lane >> 5;
        for (int r = 0; r < 16; r++) {
            const int il = w * 16 + r;
            const int ig = i0 + il;
            float qv = q[((size_t)bh * SEQ + ig) * DIM + lane];
            float ssq = qv * qv;
            #pragma unroll
            for (int m2 = 1; m2 < 64; m2 <<= 1) ssq += __shfl_xor(ssq, m2);
            float qn = qv / fmaxf(sqrtf(ssq), 1e-12f);
            qnT[lane][il] = qn;

            // sim_mem: lane covers (knn j = jm, d-half = half)
            const float* mk = mem_kv + ((size_t)bh * SEQ + ig) * (KNN * 2 * DIM)
                            + jm * (2 * DIM) + half * 32;
            float part = 0.f;
            #pragma unroll
            for (int t = 0; t < 8; t++) {
                F4 kv; kv.v = *(const float4*)(mk + 4 * t);
                #pragma unroll
                for (int e = 0; e < 4; e++)
                    part += kv.f[e] * qnT[half * 32 + 4 * t + e][il];
            }
            part += __shfl_xor(part, 32);  // both halves now hold full dot
            float sim = part * scale;
            size_t mmoff = ((size_t)bh * SEQ + ig) * KNN + jm;
            bool mmv = mask_is_int ? (((const int*)mem_mask)[mmoff] != 0)
                                   : (((const unsigned char*)mem_mask)[mmoff] != 0);
            float sv = mmv ? sim : NEGF;
            float mx = sv;
            #pragma unroll
            for (int m2 = 1; m2 < 32; m2 <<= 1) mx = fmaxf(mx, __shfl_xor(mx, m2));
            float p = expf(sv - mx);   // all-masked row -> p=1 garbage, zeroed at merge
            float ls = p;
            #pragma unroll
            for (int m2 = 1; m2 < 32; m2 <<= 1) ls += __shfl_xor(ls, m2);
            if (half == 0) pmem[w][jm] = p;
            // weighted mem_v: lane -> d
            const float* mv = mem_kv + ((size_t)bh * SEQ + ig) * (KNN * 2 * DIM) + DIM + lane;
            float accd = 0.f;
            #pragma unroll
            for (int j = 0; j < KNN; j++)
                accd += pmem[w][j] * mv[(size_t)j * (2 * DIM)];
            maccs[il][lane] = accd;
            if (lane == 0) { mmem_s[il] = mx; lmem_s[il] = ls; }
        }
    }

    // ---------- Phase B: local causal flash ----------
    const int rg = lane >> 4;             // row group (4 rows each)
    const int cg = lane & 15;             // col/d group (4 each)
    float acc[4][4] = {};
    float pv[4][4];
    float mrow[4], lrow[4];
    #pragma unroll
    for (int rr = 0; rr < 4; rr++) { mrow[rr] = NEGF; lrow[rr] = 0.f; }

    for (int jt = 0; jt <= qt; jt++) {
        __syncthreads();
        {   // stage kn tile (transposed layout direct from ws)
            const int kk = tid >> 2, chunk = tid & 3;
            const float* src = knTg + ((size_t)b * DIM + kk) * SEQ + jt * QT + chunk * 16;
            float4 c0 = ((const float4*)src)[0];
            float4 c1 = ((const float4*)src)[1];
            float4 c2 = ((const float4*)src)[2];
            float4 c3 = ((const float4*)src)[3];
            float* dst = &knT_s[kk][chunk * 16];
            ((float4*)dst)[0] = c0; ((float4*)dst)[1] = c1;
            ((float4*)dst)[2] = c2; ((float4*)dst)[3] = c3;
        }
        __syncthreads();

        float sv[4][4] = {};
        #pragma unroll 4
        for (int kk = 0; kk < DIM; kk++) {
            F4 qv4, kv4;
            qv4.v = *(const float4*)&qnT[kk][w * 16 + rg * 4];
            kv4.v = *(const float4*)&knT_s[kk][cg * 4];
            #pragma unroll
            for (int rr = 0; rr < 4; rr++)
                #pragma unroll
                for (int cc = 0; cc < 4; cc++)
                    sv[rr][cc] += qv4.f[rr] * kv4.f[cc];
        }

        const int jbase = jt * QT;
        float maskv[4];
        #pragma unroll
        for (int cc = 0; cc < 4; cc++) maskv[cc] = mask[b * SEQ + jbase + cg * 4 + cc];
        #pragma unroll
        for (int rr = 0; rr < 4; rr++)
            #pragma unroll
            for (int cc = 0; cc < 4; cc++)
                sv[rr][cc] = sv[rr][cc] * scale + NEGF * (1.f - maskv[cc]);
        if (jt == qt) {
            #pragma unroll
            for (int rr = 0; rr < 4; rr++) {
                int ig = i0 + w * 16 + rg * 4 + rr;
                #pragma unroll
                for (int cc = 0; cc < 4; cc++) {
                    int jg = jbase + cg * 4 + cc;
                    if (jg > ig) sv[rr][cc] = NEGF;
                }
            }
        }

        #pragma unroll
        for (int rr = 0; rr < 4; rr++) {
            float mx = fmaxf(fmaxf(sv[rr][0], sv[rr][1]), fmaxf(sv[rr][2], sv[rr][3]));
            #pragma unroll
            for (int m2 = 1; m2 < 16; m2 <<= 1) mx = fmaxf(mx, __shfl_xor(mx, m2));
            float mnew = fmaxf(mrow[rr], mx);
            float corr = expf(mrow[rr] - mnew);
            float psum = 0.f;
            #pragma unroll
            for (int cc = 0; cc < 4; cc++) {
                float p = expf(sv[rr][cc] - mnew);
                pv[rr][cc] = p;
                psum += p;
            }
            #pragma unroll
            for (int m2 = 1; m2 < 16; m2 <<= 1) psum += __shfl_xor(psum, m2);
            mrow[rr] = mnew;
            lrow[rr] = lrow[rr] * corr + psum;
            #pragma unroll
            for (int dd = 0; dd < 4; dd++) acc[rr][dd] *= corr;
        }

        // PV in two 32-col halves via per-wave LDS transpose; v straight from L2
        #pragma unroll
        for (int hf = 0; hf < 2; hf++) {
            if ((cg >> 3) == hf) {
                const int c8 = cg & 7;
                #pragma unroll
                for (int rr = 0; rr < 4; rr++) {
                    F4 pw;
                    #pragma unroll
                    for (int cc = 0; cc < 4; cc++) pw.f[cc] = pv[rr][cc];
                    *(float4*)&ptile[w][rg * 4 + rr][c8 * 4] = pw.v;
                }
            }
            #pragma unroll 2
            for (int j4 = 0; j4 < 8; j4++) {
                F4 pf[4];
                #pragma unroll
                for (int rr = 0; rr < 4; rr++)
                    pf[rr].v = *(const float4*)&ptile[w][rg * 4 + rr][j4 * 4];
                F4 vv[4];
                #pragma unroll
                for (int e = 0; e < 4; e++)
                    vv[e].v = *(const float4*)(v + ((size_t)b * SEQ + jbase + hf * 32 + j4 * 4 + e) * DIM + cg * 4);
                #pragma unroll
                for (int rr = 0; rr < 4; rr++)
                    #pragma unroll
                    for (int e = 0; e < 4; e++)
                        #pragma unroll
                        for (int dd = 0; dd < 4; dd++)
                            acc[rr][dd] += pf[rr].f[e] * vv[e].f[dd];
            }
        }
    }

    // ---------- merge local + mem softmax groups, write out ----------
    #pragma unroll
    for (int rr = 0; rr < 4; rr++) {
        const int il = w * 16 + rg * 4 + rr;
        float mm = mmem_s[il], lm = lmem_s[il];
        float M = fmaxf(mrow[rr], mm);
        float el = expf(mrow[rr] - M);
        float em = expf(mm - M);
        float denom = lrow[rr] * el + lm * em;
        float inv = 1.f / denom;
        F4 mc; mc.v = *(const float4*)&maccs[il][cg * 4];
        F4 o;
        #pragma unroll
        for (int dd = 0; dd < 4; dd++)
            o.f[dd] = (acc[rr][dd] * el + mc.f[dd] * em) * inv;
        *(float4*)(out + ((size_t)bh * SEQ + i0 + il) * DIM + cg * 4) = o.v;
    }
}

extern "C" void kernel_launch(void* const* d_in, const int* in_sizes, int n_in,
                              void* d_out, int out_size, void* d_ws, size_t ws_size,
                              hipStream_t stream) {
    const float* q           = (const float*)d_in[0];
    const float* k           = (const float*)d_in[1];
    const float* v           = (const float*)d_in[2];
    const float* scale_param = (const float*)d_in[3];
    const float* mem_kv      = (const float*)d_in[4];
    const float* mask        = (const float*)d_in[5];
    const void*  mem_mask    = d_in[6];
    float* out = (float*)d_out;

    int* flag  = (int*)d_ws;
    float* knT = (float*)((char*)d_ws + 64);

    prep_kernel<<<dim3(BATCH * SEQ / 4), dim3(256), 0, stream>>>(
        k, (const unsigned char*)mem_mask, knT, flag);
    attn_kernel<<<dim3(BATCH * HEADS * (SEQ / QT)), dim3(256), 0, stream>>>(
        q, v, scale_param, mem_kv, mask, mem_mask, knT, flag, out);
}

// Round 3
// 192.048 us; speedup vs baseline: 2.1449x; 2.1449x over previous
//
#include <hip/hip_runtime.h>
#include <float.h>

#define HEADS 8
#define DIM 64
#define BATCH 2
#define SEQ 2048
#define KNN 32
#define QT 32
#define KT 64
#define NEGF (-3.402823466e38f)

typedef float f32x4 __attribute__((ext_vector_type(4)));
typedef __bf16 bf16x8 __attribute__((ext_vector_type(8)));

union F4 { float4 v; float f[4]; };
union S8 { bf16x8 b; unsigned int u[4]; unsigned short us[8]; uint4 u4; uint2 u2[2]; };

__device__ __forceinline__ unsigned short f2bf(float x) {
    unsigned int u = __float_as_uint(x);
    u = (u + 0x7fffu + ((u >> 16) & 1u)) >> 16;
    return (unsigned short)u;
}

// ws: [0..4) int flag (1 = mem_mask int32); knB bf16 (B,S,D) @256; vT bf16 (B,D,S) @256+512K
__global__ __launch_bounds__(256) void prep_kernel(const float* __restrict__ k,
                                                   const float* __restrict__ v,
                                                   const unsigned char* __restrict__ mmraw,
                                                   unsigned short* __restrict__ knB,
                                                   unsigned short* __restrict__ vT,
                                                   int* __restrict__ flag) {
    int w = threadIdx.x >> 6, lane = threadIdx.x & 63;
    int row = blockIdx.x * 4 + w;               // b*SEQ + s
    int b = row >> 11, s = row & 2047;
    float kv = k[(size_t)row * DIM + lane];
    float ssq = kv * kv;
    #pragma unroll
    for (int m = 1; m < 64; m <<= 1) ssq += __shfl_xor(ssq, m);
    float kn = kv / fmaxf(sqrtf(ssq), 1e-12f);
    knB[(size_t)row * DIM + lane] = f2bf(kn);
    float vv = v[(size_t)row * DIM + lane];
    vT[((size_t)b * DIM + lane) * SEQ + s] = f2bf(vv);
    if (blockIdx.x == 0 && w == 0) {
        int bad = 0;
        #pragma unroll
        for (int t = 0; t < 8; t++) {
            int idx = t * 64 + lane;
            if ((idx & 3) != 0 && mmraw[idx] != 0) bad = 1;
        }
        unsigned long long anybad = __ballot(bad);
        if (lane == 0) flag[0] = (anybad == 0ULL) ? 1 : 0;
    }
}

__global__ __launch_bounds__(256) void attn_kernel(
    const float* __restrict__ q,          // B,H,S,D
    const float* __restrict__ scale_param,// H
    const float* __restrict__ mem_kv,     // B,H,S,KNN,2,D
    const float* __restrict__ mask,       // B,S float
    const void*  __restrict__ mem_mask,   // B,H,S,KNN
    const unsigned short* __restrict__ knB, // B,S,D bf16 (l2-normed k)
    const unsigned short* __restrict__ vT,  // B,D,S bf16
    const int*   __restrict__ flagp,
    float* __restrict__ out)              // B,H,S,D
{
    __shared__ float qn_s[QT][DIM + 4];                  // 8.7 KB
    __shared__ float maccs[QT][DIM + 4];                 // 8.7 KB
    __shared__ float pmem[4][KNN];
    __shared__ float mmem_s[QT], lmem_s[QT];
    __shared__ unsigned short fragbuf[4][2][2][4][16][8]; // 16 KB, per-wave P in B-frag layout
    __shared__ float corr_s[4][QT];
    __shared__ float mlw[4][2][QT];
    __shared__ float linv_s[QT];

    const int tid = threadIdx.x;
    const int w = tid >> 6;
    const int lane = tid & 63;
    const int g = lane >> 4;
    const int c = lane & 15;
    const int bid = blockIdx.x;
    const int qt = 63 - (bid & 63);       // heavy tiles first
    const int bh = bid >> 6;
    const int b = bh >> 3;
    const int h = bh & 7;
    const int i0 = qt * QT;

    const float scale = expf(scale_param[h]);
    const int mask_is_int = flagp[0];

    // ---------------- Phase A: q-norm + mem branch (fp32 exact) ----------------
    {
        const int jm = lane & 31;
        const int half = lane >> 5;
        for (int r = 0; r < 8; r++) {
            const int il = w * 8 + r;
            const int ig = i0 + il;
            float qv = q[((size_t)bh * SEQ + ig) * DIM + lane];
            float ssq = qv * qv;
            #pragma unroll
            for (int m2 = 1; m2 < 64; m2 <<= 1) ssq += __shfl_xor(ssq, m2);
            float qn = qv / fmaxf(sqrtf(ssq), 1e-12f);
            qn_s[il][lane] = qn;

            const float* mkb = mem_kv + ((size_t)bh * SEQ + ig) * (KNN * 2 * DIM);
            const float* mk = mkb + jm * (2 * DIM) + half * 32;
            float part = 0.f;
            #pragma unroll
            for (int t = 0; t < 8; t++) {
                F4 kv4; kv4.v = *(const float4*)(mk + 4 * t);
                F4 qq;  qq.v  = *(const float4*)&qn_s[il][half * 32 + 4 * t];
                #pragma unroll
                for (int e = 0; e < 4; e++) part += kv4.f[e] * qq.f[e];
            }
            part += __shfl_xor(part, 32);
            float sim = part * scale;
            size_t mmoff = ((size_t)bh * SEQ + ig) * KNN + jm;
            bool mmv = mask_is_int ? (((const int*)mem_mask)[mmoff] != 0)
                                   : (((const unsigned char*)mem_mask)[mmoff] != 0);
            float sv = mmv ? sim : NEGF;
            float mx = sv;
            #pragma unroll
            for (int m2 = 1; m2 < 32; m2 <<= 1) mx = fmaxf(mx, __shfl_xor(mx, m2));
            float p = expf(sv - mx);
            float ls = p;
            #pragma unroll
            for (int m2 = 1; m2 < 32; m2 <<= 1) ls += __shfl_xor(ls, m2);
            if (half == 0) pmem[w][jm] = p;
            F4 acc4; acc4.v = make_float4(0.f, 0.f, 0.f, 0.f);
            const float* mvb = mkb + DIM + c * 4;
            #pragma unroll
            for (int t = 0; t < 8; t++) {
                int jj = t * 4 + g;
                F4 vv4; vv4.v = *(const float4*)(mvb + (size_t)jj * (2 * DIM));
                float pw = pmem[w][jj];
                #pragma unroll
                for (int e = 0; e < 4; e++) acc4.f[e] += pw * vv4.f[e];
            }
            #pragma unroll
            for (int e = 0; e < 4; e++) {
                acc4.f[e] += __shfl_xor(acc4.f[e], 16);
                acc4.f[e] += __shfl_xor(acc4.f[e], 32);
            }
            if (lane < 16) *(float4*)&maccs[il][c * 4] = acc4.v;
            if (lane == 0) { mmem_s[il] = mx; lmem_s[il] = ls; }
        }
    }
    __syncthreads();

    // ---------------- Q A-fragments (registers, bf16) ----------------
    bf16x8 qa[2][2];
    #pragma unroll
    for (int mt = 0; mt < 2; mt++)
        #pragma unroll
        for (int kc = 0; kc < 2; kc++) {
            const float* qp = &qn_s[mt * 16 + c][kc * 32 + g * 8];
            F4 a0, a1; a0.v = *(const float4*)qp; a1.v = *(const float4*)(qp + 4);
            S8 t;
            #pragma unroll
            for (int e = 0; e < 4; e++) { t.us[e] = f2bf(a0.f[e]); t.us[4 + e] = f2bf(a1.f[e]); }
            qa[mt][kc] = t.b;
        }

    // ---------------- Flash over key tiles (waves split jt) ----------------
    f32x4 oacc[4][2];
    #pragma unroll
    for (int mtd = 0; mtd < 4; mtd++)
        #pragma unroll
        for (int ni = 0; ni < 2; ni++)
            #pragma unroll
            for (int r = 0; r < 4; r++) oacc[mtd][ni][r] = 0.f;
    float mrow[2][4], lrow[2][4];
    #pragma unroll
    for (int mt = 0; mt < 2; mt++)
        #pragma unroll
        for (int r = 0; r < 4; r++) { mrow[mt][r] = NEGF; lrow[mt][r] = 0.f; }

    const int nkt = ((i0 + QT - 1) >> 6) + 1;
    const unsigned short* knBb = knB + (size_t)b * SEQ * DIM;
    const unsigned short* vTb  = vT  + (size_t)b * DIM * SEQ;

    for (int jt = w; jt < nkt; jt += 4) {
        const int jb = jt * KT;

        // V A-frags from vT (issue early; L2-resident)
        bf16x8 va[4][2];
        #pragma unroll
        for (int mtd = 0; mtd < 4; mtd++)
            #pragma unroll
            for (int kk2 = 0; kk2 < 2; kk2++) {
                const unsigned short* vp = vTb + (size_t)(mtd * 16 + c) * SEQ + jb + kk2 * 32 + 4 * g;
                S8 t; t.u2[0] = *(const uint2*)vp; t.u2[1] = *(const uint2*)(vp + 16);
                va[mtd][kk2] = t.b;
            }

        // QK^T via MFMA
        f32x4 sacc[2][4];
        #pragma unroll
        for (int mt = 0; mt < 2; mt++)
            #pragma unroll
            for (int nt = 0; nt < 4; nt++)
                #pragma unroll
                for (int r = 0; r < 4; r++) sacc[mt][nt][r] = 0.f;
        #pragma unroll
        for (int kc = 0; kc < 2; kc++) {
            #pragma unroll
            for (int nt = 0; nt < 4; nt++) {
                S8 kb; kb.u4 = *(const uint4*)(knBb + (size_t)(jb + nt * 16 + c) * DIM + kc * 32 + g * 8);
                #pragma unroll
                for (int mt = 0; mt < 2; mt++)
                    sacc[mt][nt] = __builtin_amdgcn_mfma_f32_16x16x32_bf16(qa[mt][kc], kb.b, sacc[mt][nt], 0, 0, 0);
            }
        }

        // scale + key-mask + causal
        float mv4[4];
        #pragma unroll
        for (int nt = 0; nt < 4; nt++) mv4[nt] = mask[b * SEQ + jb + nt * 16 + c];
        const bool docausal = (jb + 63 > i0);
        float corr[2][4];
        #pragma unroll
        for (int mt = 0; mt < 2; mt++) {
            #pragma unroll
            for (int nt = 0; nt < 4; nt++)
                #pragma unroll
                for (int r = 0; r < 4; r++) {
                    float s = sacc[mt][nt][r] * scale + NEGF * (1.f - mv4[nt]);
                    if (docausal) {
                        int j = jb + nt * 16 + c;
                        int i = i0 + mt * 16 + 4 * g + r;
                        if (j > i) s = NEGF;
                    }
                    sacc[mt][nt][r] = s;
                }
            #pragma unroll
            for (int r = 0; r < 4; r++) {
                float rmax = fmaxf(fmaxf(sacc[mt][0][r], sacc[mt][1][r]),
                                   fmaxf(sacc[mt][2][r], sacc[mt][3][r]));
                #pragma unroll
                for (int m2 = 1; m2 < 16; m2 <<= 1) rmax = fmaxf(rmax, __shfl_xor(rmax, m2));
                float mnew = fmaxf(mrow[mt][r], rmax);
                corr[mt][r] = expf(mrow[mt][r] - mnew);
                mrow[mt][r] = mnew;
            }
        }

        // P = exp(S - m); write into per-wave B-frag layout; row sums
        #pragma unroll
        for (int mt = 0; mt < 2; mt++) {
            float psum[4] = {0.f, 0.f, 0.f, 0.f};
            #pragma unroll
            for (int nt = 0; nt < 4; nt++)
                #pragma unroll
                for (int r = 0; r < 4; r++) {
                    float p = expf(sacc[mt][nt][r] - mrow[mt][r]);
                    psum[r] += p;
                    fragbuf[w][mt][nt >> 1][c >> 2][4 * g + r][(c & 3) + 4 * (nt & 1)] = f2bf(p);
                }
            #pragma unroll
            for (int r = 0; r < 4; r++) {
                float ps = psum[r];
                #pragma unroll
                for (int m2 = 1; m2 < 16; m2 <<= 1) ps += __shfl_xor(ps, m2);
                lrow[mt][r] = lrow[mt][r] * corr[mt][r] + ps;
            }
        }

        // broadcast per-row rescale factors to all lanes (oacc is i-in-cols)
        if (c == 0) {
            #pragma unroll
            for (int mt = 0; mt < 2; mt++)
                #pragma unroll
                for (int r = 0; r < 4; r++)
                    corr_s[w][mt * 16 + 4 * g + r] = corr[mt][r];
        }
        float cf0 = corr_s[w][c];
        float cf1 = corr_s[w][16 + c];
        #pragma unroll
        for (int mtd = 0; mtd < 4; mtd++)
            #pragma unroll
            for (int r = 0; r < 4; r++) { oacc[mtd][0][r] *= cf0; oacc[mtd][1][r] *= cf1; }

        // PV: O^T += V^T · P^T via MFMA
        #pragma unroll
        for (int kk2 = 0; kk2 < 2; kk2++)
            #pragma unroll
            for (int ni = 0; ni < 2; ni++) {
                S8 pb; pb.u4 = *(const uint4*)&fragbuf[w][ni][kk2][g][c][0];
                #pragma unroll
                for (int mtd = 0; mtd < 4; mtd++)
                    oacc[mtd][ni] = __builtin_amdgcn_mfma_f32_16x16x32_bf16(va[mtd][kk2], pb.b, oacc[mtd][ni], 0, 0, 0);
            }
    }

    // ---------------- merge: 4 wave-partials + mem branch ----------------
    if (c == 0) {
        #pragma unroll
        for (int mt = 0; mt < 2; mt++)
            #pragma unroll
            for (int r = 0; r < 4; r++) {
                mlw[w][0][mt * 16 + 4 * g + r] = mrow[mt][r];
                mlw[w][1][mt * 16 + 4 * g + r] = lrow[mt][r];
            }
    }
    __syncthreads();
    {
        int i = tid >> 3;
        int d0 = (tid & 7) * 8;
        float mM = mmem_s[i];
        #pragma unroll
        for (int w2 = 0; w2 < 4; w2++) mM = fmaxf(mM, mlw[w2][0][i]);
        float em = expf(mmem_s[i] - mM);
        float L = lmem_s[i] * em;
        #pragma unroll
        for (int w2 = 0; w2 < 4; w2++) L += mlw[w2][1][i] * expf(mlw[w2][0][i] - mM);
        #pragma unroll
        for (int e = 0; e < 8; e++) maccs[i][d0 + e] *= em;
        if ((tid & 7) == 0) linv_s[i] = 1.f / L;
        if ((tid & 7) == 1) corr_s[0][i] = mM;   // stash global max
    }
    __syncthreads();
    float ew0 = expf(mlw[w][0][c]      - corr_s[0][c]);
    float ew1 = expf(mlw[w][0][16 + c] - corr_s[0][16 + c]);
    for (int w2 = 0; w2 < 4; w2++) {
        if (w == w2) {
            #pragma unroll
            for (int mtd = 0; mtd < 4; mtd++)
                #pragma unroll
                for (int r = 0; r < 4; r++) {
                    maccs[c][mtd * 16 + 4 * g + r]      += oacc[mtd][0][r] * ew0;
                    maccs[16 + c][mtd * 16 + 4 * g + r] += oacc[mtd][1][r] * ew1;
                }
        }
        __syncthreads();
    }
    {
        int i = tid >> 3;
        int d0 = (tid & 7) * 8;
        float inv = linv_s[i];
        F4 o0, o1;
        o0.v = *(const float4*)&maccs[i][d0];
        o1.v = *(const float4*)&maccs[i][d0 + 4];
        #pragma unroll
        for (int e = 0; e < 4; e++) { o0.f[e] *= inv; o1.f[e] *= inv; }
        float* op = out + ((size_t)bh * SEQ + i0 + i) * DIM + d0;
        *(float4*)op = o0.v;
        *(float4*)(op + 4) = o1.v;
    }
}

extern "C" void kernel_launch(void* const* d_in, const int* in_sizes, int n_in,
                              void* d_out, int out_size, void* d_ws, size_t ws_size,
                              hipStream_t stream) {
    const float* q           = (const float*)d_in[0];
    const float* k           = (const float*)d_in[1];
    const float* v           = (const float*)d_in[2];
    const float* scale_param = (const float*)d_in[3];
    const float* mem_kv      = (const float*)d_in[4];
    const float* mask        = (const float*)d_in[5];
    const void*  mem_mask    = d_in[6];
    float* out = (float*)d_out;

    int* flag = (int*)d_ws;
    unsigned short* knB = (unsigned short*)((char*)d_ws + 256);
    unsigned short* vT  = (unsigned short*)((char*)d_ws + 256 + (size_t)BATCH * SEQ * DIM * 2);

    prep_kernel<<<dim3(BATCH * SEQ / 4), dim3(256), 0, stream>>>(
        k, v, (const unsigned char*)mem_mask, knB, vT, flag);
    attn_kernel<<<dim3(BATCH * HEADS * (SEQ / QT)), dim3(256), 0, stream>>>(
        q, scale_param, mem_kv, mask, mem_mask, knB, vT, flag, out);
}

// Round 4
// 186.891 us; speedup vs baseline: 2.2041x; 1.0276x over previous
//
#include <hip/hip_runtime.h>
#include <float.h>

#define HEADS 8
#define DIM 64
#define BATCH 2
#define SEQ 2048
#define KNN 32
#define QT 32
#define KT 64
#define NEGF (-3.402823466e38f)

typedef float f32x4 __attribute__((ext_vector_type(4)));
typedef __bf16 bf16x8 __attribute__((ext_vector_type(8)));

union F4 { float4 v; float f[4]; };
union S8 { bf16x8 b; unsigned int u[4]; unsigned short us[8]; uint4 u4; uint2 u2[2]; };

__device__ __forceinline__ unsigned short f2bf(float x) {
    unsigned int u = __float_as_uint(x);
    u = (u + 0x7fffu + ((u >> 16) & 1u)) >> 16;
    return (unsigned short)u;
}

// ws: [0..4) int flag (1 = mem_mask int32); knB bf16 (B,S,D) @256; vT bf16 (B,D,S) @256+512K
__global__ __launch_bounds__(256) void prep_kernel(const float* __restrict__ k,
                                                   const float* __restrict__ v,
                                                   const unsigned char* __restrict__ mmraw,
                                                   unsigned short* __restrict__ knB,
                                                   unsigned short* __restrict__ vT,
                                                   int* __restrict__ flag) {
    __shared__ float vt_s[64][65];
    const int w = threadIdx.x >> 6, lane = threadIdx.x & 63;
    const int s0 = blockIdx.x * 64;       // global row index b*SEQ+s
    const int b = s0 >> 11;
    for (int rr = 0; rr < 16; rr++) {
        const int sl = w * 16 + rr;
        const int row = s0 + sl;
        float kv = k[(size_t)row * DIM + lane];
        float ssq = kv * kv;
        #pragma unroll
        for (int m = 1; m < 64; m <<= 1) ssq += __shfl_xor(ssq, m);
        float kn = kv / fmaxf(sqrtf(ssq), 1e-12f);
        knB[(size_t)row * DIM + lane] = f2bf(kn);
        vt_s[sl][lane] = v[(size_t)row * DIM + lane];
    }
    __syncthreads();
    {   // transposed V write: thread -> (d, 16-s chunk), 32B contiguous stores
        const int d = threadIdx.x >> 2;
        const int sc = (threadIdx.x & 3) * 16;
        const int s_base = s0 & 2047;
        unsigned short tmp[16];
        #pragma unroll
        for (int e = 0; e < 16; e++) tmp[e] = f2bf(vt_s[sc + e][d]);
        unsigned short* dst = vT + ((size_t)b * DIM + d) * SEQ + s_base + sc;
        *(uint4*)dst = *(uint4*)&tmp[0];
        *(uint4*)(dst + 8) = *(uint4*)&tmp[8];
    }
    if (blockIdx.x == 0 && w == 0) {
        int bad = 0;
        #pragma unroll
        for (int t = 0; t < 8; t++) {
            int idx = t * 64 + lane;
            if ((idx & 3) != 0 && mmraw[idx] != 0) bad = 1;
        }
        unsigned long long anybad = __ballot(bad);
        if (lane == 0) flag[0] = (anybad == 0ULL) ? 1 : 0;
    }
}

__global__ __launch_bounds__(256) void attn_kernel(
    const float* __restrict__ q,          // B,H,S,D
    const float* __restrict__ scale_param,// H
    const float* __restrict__ mem_kv,     // B,H,S,KNN,2,D
    const float* __restrict__ mask,       // B,S float
    const void*  __restrict__ mem_mask,   // B,H,S,KNN
    const unsigned short* __restrict__ knB, // B,S,D bf16 (l2-normed k)
    const unsigned short* __restrict__ vT,  // B,D,S bf16
    const int*   __restrict__ flagp,
    float* __restrict__ out)              // B,H,S,D
{
    __shared__ float qn_s[QT][DIM + 4];
    __shared__ float maccs[QT][DIM + 4];
    __shared__ float mmem_s[QT], lmem_s[QT];
    __shared__ unsigned short fragbuf[4][2][2][4][16][8]; // per-wave P in B-frag layout
    __shared__ float corr_s[4][QT];
    __shared__ float mlw[4][2][QT];
    __shared__ float linv_s[QT];

    const int tid = threadIdx.x;
    const int w = tid >> 6;
    const int lane = tid & 63;
    const int g = lane >> 4;
    const int c = lane & 15;
    const int bid = blockIdx.x;
    const int qt = 63 - (bid & 63);       // heavy tiles first
    const int bh = bid >> 6;
    const int b = bh >> 3;
    const int h = bh & 7;
    const int i0 = qt * QT;

    const float scale = __expf(scale_param[h]);
    const int mask_is_int = flagp[0];

    // ---- Phase A: q-norm + mem branch, fully-coalesced mem_kv streaming ----
    {
        const int i16 = lane & 15;        // d-quarter
        const int kv  = (lane >> 4) & 1;  // 0 = k-part, 1 = v-part
        const int h2  = lane >> 5;        // j parity
        for (int r = 0; r < 8; r++) {
            const int il = w * 8 + r;
            const int ig = i0 + il;
            // q l2-norm
            float qv = q[((size_t)bh * SEQ + ig) * DIM + lane];
            float ssq = qv * qv;
            #pragma unroll
            for (int m2 = 1; m2 < 64; m2 <<= 1) ssq += __shfl_xor(ssq, m2);
            float qn = qv / fmaxf(sqrtf(ssq), 1e-12f);
            qn_s[il][lane] = qn;
            // mem_mask bits (bit j of mb)
            size_t mmrow = ((size_t)bh * SEQ + ig) * KNN;
            bool mybit = mask_is_int ? (((const int*)mem_mask)[mmrow + (lane & 31)] != 0)
                                     : (((const unsigned char*)mem_mask)[mmrow + (lane & 31)] != 0);
            unsigned long long mb = __ballot(mybit);
            // 16 contiguous 1KB wave loads: chunk c0 = t*64+lane -> j=2t+h2, kv, d0=i16*4
            const float* rowp = mem_kv + ((size_t)bh * SEQ + ig) * (KNN * 2 * DIM);
            F4 dat[16];
            #pragma unroll
            for (int t = 0; t < 16; t++)
                dat[t].v = *(const float4*)(rowp + (size_t)(t * 64 + lane) * 4);
            F4 qd; qd.v = *(const float4*)&qn_s[il][i16 * 4];
            // k-dots (valid in k-lanes): s_j for j = 2t + h2
            float pj[16];
            #pragma unroll
            for (int t = 0; t < 16; t++) {
                float part = dat[t].f[0] * qd.f[0] + dat[t].f[1] * qd.f[1]
                           + dat[t].f[2] * qd.f[2] + dat[t].f[3] * qd.f[3];
                part += __shfl_xor(part, 1);
                part += __shfl_xor(part, 2);
                part += __shfl_xor(part, 4);
                part += __shfl_xor(part, 8);
                float s = part * scale;
                int j = 2 * t + h2;
                if (!((mb >> j) & 1ull)) s = NEGF;
                pj[t] = s;
            }
            // row max over 32 j (combine parities via xor 32)
            float mx = pj[0];
            #pragma unroll
            for (int t = 1; t < 16; t++) mx = fmaxf(mx, pj[t]);
            mx = fmaxf(mx, __shfl_xor(mx, 32));
            // p = exp(s - mx), row sum
            float ls = 0.f;
            #pragma unroll
            for (int t = 0; t < 16; t++) {
                float p = __expf(pj[t] - mx);
                pj[t] = p;
                ls += p;
            }
            ls += __shfl_xor(ls, 32);
            // weighted V (valid in v-lanes): p from partner k-lane via xor 16
            float a0 = 0.f, a1 = 0.f, a2 = 0.f, a3 = 0.f;
            #pragma unroll
            for (int t = 0; t < 16; t++) {
                float p = __shfl_xor(pj[t], 16);
                a0 += p * dat[t].f[0];
                a1 += p * dat[t].f[1];
                a2 += p * dat[t].f[2];
                a3 += p * dat[t].f[3];
            }
            a0 += __shfl_xor(a0, 32);
            a1 += __shfl_xor(a1, 32);
            a2 += __shfl_xor(a2, 32);
            a3 += __shfl_xor(a3, 32);
            if (kv == 1 && h2 == 0) {
                F4 o; o.f[0] = a0; o.f[1] = a1; o.f[2] = a2; o.f[3] = a3;
                *(float4*)&maccs[il][i16 * 4] = o.v;
            }
            if (lane == 0) { mmem_s[il] = mx; lmem_s[il] = ls; }
        }
    }
    __syncthreads();

    // ---------------- Q A-fragments (registers, bf16) ----------------
    bf16x8 qa[2][2];
    #pragma unroll
    for (int mt = 0; mt < 2; mt++)
        #pragma unroll
        for (int kc = 0; kc < 2; kc++) {
            const float* qp = &qn_s[mt * 16 + c][kc * 32 + g * 8];
            F4 a0, a1; a0.v = *(const float4*)qp; a1.v = *(const float4*)(qp + 4);
            S8 t;
            #pragma unroll
            for (int e = 0; e < 4; e++) { t.us[e] = f2bf(a0.f[e]); t.us[4 + e] = f2bf(a1.f[e]); }
            qa[mt][kc] = t.b;
        }

    // ---------------- Flash over key tiles (waves split jt) ----------------
    f32x4 oacc[4][2];
    #pragma unroll
    for (int mtd = 0; mtd < 4; mtd++)
        #pragma unroll
        for (int ni = 0; ni < 2; ni++)
            #pragma unroll
            for (int r = 0; r < 4; r++) oacc[mtd][ni][r] = 0.f;
    float mrow[2][4], lrow[2][4];
    #pragma unroll
    for (int mt = 0; mt < 2; mt++)
        #pragma unroll
        for (int r = 0; r < 4; r++) { mrow[mt][r] = NEGF; lrow[mt][r] = 0.f; }

    const int nkt = ((i0 + QT - 1) >> 6) + 1;
    const unsigned short* knBb = knB + (size_t)b * SEQ * DIM;
    const unsigned short* vTb  = vT  + (size_t)b * DIM * SEQ;

    for (int jt = w; jt < nkt; jt += 4) {
        const int jb = jt * KT;

        bf16x8 va[4][2];
        #pragma unroll
        for (int mtd = 0; mtd < 4; mtd++)
            #pragma unroll
            for (int kk2 = 0; kk2 < 2; kk2++) {
                const unsigned short* vp = vTb + (size_t)(mtd * 16 + c) * SEQ + jb + kk2 * 32 + 4 * g;
                S8 t; t.u2[0] = *(const uint2*)vp; t.u2[1] = *(const uint2*)(vp + 16);
                va[mtd][kk2] = t.b;
            }

        f32x4 sacc[2][4];
        #pragma unroll
        for (int mt = 0; mt < 2; mt++)
            #pragma unroll
            for (int nt = 0; nt < 4; nt++)
                #pragma unroll
                for (int r = 0; r < 4; r++) sacc[mt][nt][r] = 0.f;
        #pragma unroll
        for (int kc = 0; kc < 2; kc++) {
            #pragma unroll
            for (int nt = 0; nt < 4; nt++) {
                S8 kb; kb.u4 = *(const uint4*)(knBb + (size_t)(jb + nt * 16 + c) * DIM + kc * 32 + g * 8);
                #pragma unroll
                for (int mt = 0; mt < 2; mt++)
                    sacc[mt][nt] = __builtin_amdgcn_mfma_f32_16x16x32_bf16(qa[mt][kc], kb.b, sacc[mt][nt], 0, 0, 0);
            }
        }

        float mv4[4];
        #pragma unroll
        for (int nt = 0; nt < 4; nt++) mv4[nt] = mask[b * SEQ + jb + nt * 16 + c];
        const bool docausal = (jb + 63 > i0);
        float corr[2][4];
        #pragma unroll
        for (int mt = 0; mt < 2; mt++) {
            #pragma unroll
            for (int nt = 0; nt < 4; nt++)
                #pragma unroll
                for (int r = 0; r < 4; r++) {
                    float s = sacc[mt][nt][r] * scale + NEGF * (1.f - mv4[nt]);
                    if (docausal) {
                        int j = jb + nt * 16 + c;
                        int i = i0 + mt * 16 + 4 * g + r;
                        if (j > i) s = NEGF;
                    }
                    sacc[mt][nt][r] = s;
                }
            #pragma unroll
            for (int r = 0; r < 4; r++) {
                float rmax = fmaxf(fmaxf(sacc[mt][0][r], sacc[mt][1][r]),
                                   fmaxf(sacc[mt][2][r], sacc[mt][3][r]));
                #pragma unroll
                for (int m2 = 1; m2 < 16; m2 <<= 1) rmax = fmaxf(rmax, __shfl_xor(rmax, m2));
                float mnew = fmaxf(mrow[mt][r], rmax);
                corr[mt][r] = __expf(mrow[mt][r] - mnew);
                mrow[mt][r] = mnew;
            }
        }

        #pragma unroll
        for (int mt = 0; mt < 2; mt++) {
            float psum[4] = {0.f, 0.f, 0.f, 0.f};
            #pragma unroll
            for (int nt = 0; nt < 4; nt++)
                #pragma unroll
                for (int r = 0; r < 4; r++) {
                    float p = __expf(sacc[mt][nt][r] - mrow[mt][r]);
                    psum[r] += p;
                    fragbuf[w][mt][nt >> 1][c >> 2][4 * g + r][(c & 3) + 4 * (nt & 1)] = f2bf(p);
                }
            #pragma unroll
            for (int r = 0; r < 4; r++) {
                float ps = psum[r];
                #pragma unroll
                for (int m2 = 1; m2 < 16; m2 <<= 1) ps += __shfl_xor(ps, m2);
                lrow[mt][r] = lrow[mt][r] * corr[mt][r] + ps;
            }
        }

        if (c == 0) {
            #pragma unroll
            for (int mt = 0; mt < 2; mt++)
                #pragma unroll
                for (int r = 0; r < 4; r++)
                    corr_s[w][mt * 16 + 4 * g + r] = corr[mt][r];
        }
        float cf0 = corr_s[w][c];
        float cf1 = corr_s[w][16 + c];
        #pragma unroll
        for (int mtd = 0; mtd < 4; mtd++)
            #pragma unroll
            for (int r = 0; r < 4; r++) { oacc[mtd][0][r] *= cf0; oacc[mtd][1][r] *= cf1; }

        #pragma unroll
        for (int kk2 = 0; kk2 < 2; kk2++)
            #pragma unroll
            for (int ni = 0; ni < 2; ni++) {
                S8 pb; pb.u4 = *(const uint4*)&fragbuf[w][ni][kk2][g][c][0];
                #pragma unroll
                for (int mtd = 0; mtd < 4; mtd++)
                    oacc[mtd][ni] = __builtin_amdgcn_mfma_f32_16x16x32_bf16(va[mtd][kk2], pb.b, oacc[mtd][ni], 0, 0, 0);
            }
    }

    // ---------------- merge: 4 wave-partials + mem branch ----------------
    if (c == 0) {
        #pragma unroll
        for (int mt = 0; mt < 2; mt++)
            #pragma unroll
            for (int r = 0; r < 4; r++) {
                mlw[w][0][mt * 16 + 4 * g + r] = mrow[mt][r];
                mlw[w][1][mt * 16 + 4 * g + r] = lrow[mt][r];
            }
    }
    __syncthreads();
    {
        int i = tid >> 3;
        int d0 = (tid & 7) * 8;
        float mM = mmem_s[i];
        #pragma unroll
        for (int w2 = 0; w2 < 4; w2++) mM = fmaxf(mM, mlw[w2][0][i]);
        float em = __expf(mmem_s[i] - mM);
        float L = lmem_s[i] * em;
        #pragma unroll
        for (int w2 = 0; w2 < 4; w2++) L += mlw[w2][1][i] * __expf(mlw[w2][0][i] - mM);
        #pragma unroll
        for (int e = 0; e < 8; e++) maccs[i][d0 + e] *= em;
        if ((tid & 7) == 0) linv_s[i] = 1.f / L;
        if ((tid & 7) == 1) corr_s[0][i] = mM;   // stash global max
    }
    __syncthreads();
    float ew0 = __expf(mlw[w][0][c]      - corr_s[0][c]);
    float ew1 = __expf(mlw[w][0][16 + c] - corr_s[0][16 + c]);
    for (int w2 = 0; w2 < 4; w2++) {
        if (w == w2) {
            #pragma unroll
            for (int mtd = 0; mtd < 4; mtd++)
                #pragma unroll
                for (int r = 0; r < 4; r++) {
                    maccs[c][mtd * 16 + 4 * g + r]      += oacc[mtd][0][r] * ew0;
                    maccs[16 + c][mtd * 16 + 4 * g + r] += oacc[mtd][1][r] * ew1;
                }
        }
        __syncthreads();
    }
    {
        int i = tid >> 3;
        int d0 = (tid & 7) * 8;
        float inv = linv_s[i];
        F4 o0, o1;
        o0.v = *(const float4*)&maccs[i][d0];
        o1.v = *(const float4*)&maccs[i][d0 + 4];
        #pragma unroll
        for (int e = 0; e < 4; e++) { o0.f[e] *= inv; o1.f[e] *= inv; }
        float* op = out + ((size_t)bh * SEQ + i0 + i) * DIM + d0;
        *(float4*)op = o0.v;
        *(float4*)(op + 4) = o1.v;
    }
}

extern "C" void kernel_launch(void* const* d_in, const int* in_sizes, int n_in,
                              void* d_out, int out_size, void* d_ws, size_t ws_size,
                              hipStream_t stream) {
    const float* q           = (const float*)d_in[0];
    const float* k           = (const float*)d_in[1];
    const float* v           = (const float*)d_in[2];
    const float* scale_param = (const float*)d_in[3];
    const float* mem_kv      = (const float*)d_in[4];
    const float* mask        = (const float*)d_in[5];
    const void*  mem_mask    = d_in[6];
    float* out = (float*)d_out;

    int* flag = (int*)d_ws;
    unsigned short* knB = (unsigned short*)((char*)d_ws + 256);
    unsigned short* vT  = (unsigned short*)((char*)d_ws + 256 + (size_t)BATCH * SEQ * DIM * 2);

    prep_kernel<<<dim3(BATCH * SEQ / 64), dim3(256), 0, stream>>>(
        k, v, (const unsigned char*)mem_mask, knB, vT, flag);
    attn_kernel<<<dim3(BATCH * HEADS * (SEQ / QT)), dim3(256), 0, stream>>>(
        q, scale_param, mem_kv, mask, mem_mask, knB, vT, flag, out);
}

// Round 5
// 171.993 us; speedup vs baseline: 2.3950x; 1.0866x over previous
//
#include <hip/hip_runtime.h>
#include <float.h>

#define HEADS 8
#define DIM 64
#define BATCH 2
#define SEQ 2048
#define KNN 32
#define QT 32
#define KT 64
#define NEGF (-3.402823466e38f)

typedef float f32x4 __attribute__((ext_vector_type(4)));
typedef __bf16 bf16x8 __attribute__((ext_vector_type(8)));

union F4 { float4 v; f32x4 e; float f[4]; };
union S8 { bf16x8 b; unsigned int u[4]; unsigned short us[8]; uint4 u4; uint2 u2[2]; };

__device__ __forceinline__ unsigned short f2bf(float x) {
    unsigned int u = __float_as_uint(x);
    u = (u + 0x7fffu + ((u >> 16) & 1u)) >> 16;
    return (unsigned short)u;
}

// ws: [0..4) int flag (1 = mem_mask int32); knB bf16 (B,S,D) @256; vT bf16 (B,D,S) @256+512K
__global__ __launch_bounds__(256) void prep_kernel(const float* __restrict__ k,
                                                   const float* __restrict__ v,
                                                   const unsigned char* __restrict__ mmraw,
                                                   unsigned short* __restrict__ knB,
                                                   unsigned short* __restrict__ vT,
                                                   int* __restrict__ flag) {
    __shared__ float vt_s[64][65];
    const int w = threadIdx.x >> 6, lane = threadIdx.x & 63;
    const int s0 = blockIdx.x * 64;       // global row index b*SEQ+s
    const int b = s0 >> 11;
    for (int rr = 0; rr < 16; rr++) {
        const int sl = w * 16 + rr;
        const int row = s0 + sl;
        float kv = k[(size_t)row * DIM + lane];
        float ssq = kv * kv;
        #pragma unroll
        for (int m = 1; m < 64; m <<= 1) ssq += __shfl_xor(ssq, m);
        float kn = kv / fmaxf(sqrtf(ssq), 1e-12f);
        knB[(size_t)row * DIM + lane] = f2bf(kn);
        vt_s[sl][lane] = v[(size_t)row * DIM + lane];
    }
    __syncthreads();
    {   // transposed V write: thread -> (d, 16-s chunk), 32B contiguous stores
        const int d = threadIdx.x >> 2;
        const int sc = (threadIdx.x & 3) * 16;
        const int s_base = s0 & 2047;
        unsigned short tmp[16];
        #pragma unroll
        for (int e = 0; e < 16; e++) tmp[e] = f2bf(vt_s[sc + e][d]);
        unsigned short* dst = vT + ((size_t)b * DIM + d) * SEQ + s_base + sc;
        *(uint4*)dst = *(uint4*)&tmp[0];
        *(uint4*)(dst + 8) = *(uint4*)&tmp[8];
    }
    if (blockIdx.x == 0 && w == 0) {
        int bad = 0;
        #pragma unroll
        for (int t = 0; t < 8; t++) {
            int idx = t * 64 + lane;
            if ((idx & 3) != 0 && mmraw[idx] != 0) bad = 1;
        }
        unsigned long long anybad = __ballot(bad);
        if (lane == 0) flag[0] = (anybad == 0ULL) ? 1 : 0;
    }
}

__global__ __launch_bounds__(256) void attn_kernel(
    const float* __restrict__ q,          // B,H,S,D
    const float* __restrict__ scale_param,// H
    const float* __restrict__ mem_kv,     // B,H,S,KNN,2,D
    const float* __restrict__ mask,       // B,S float
    const void*  __restrict__ mem_mask,   // B,H,S,KNN
    const unsigned short* __restrict__ knB, // B,S,D bf16 (l2-normed k)
    const unsigned short* __restrict__ vT,  // B,D,S bf16
    const int*   __restrict__ flagp,
    float* __restrict__ out)              // B,H,S,D
{
    __shared__ float qn_s[QT][DIM + 4];
    __shared__ float maccs[QT][DIM + 4];
    __shared__ float mmem_s[QT], lmem_s[QT];
    __shared__ unsigned short fragbuf[4][2][2][4][16][8]; // per-wave P in B-frag layout
    __shared__ float corr_s[4][QT];
    __shared__ float mlw[4][2][QT];
    __shared__ float linv_s[QT];

    const int tid = threadIdx.x;
    const int w = tid >> 6;
    const int lane = tid & 63;
    const int g = lane >> 4;
    const int c = lane & 15;
    const int bid = blockIdx.x;
    const int qt = 63 - (bid & 63);       // heavy tiles first
    const int bh = bid >> 6;
    const int b = bh >> 3;
    const int h = bh & 7;
    const int i0 = qt * QT;

    const float scale = __expf(scale_param[h]);
    const int mask_is_int = flagp[0];

    // ---- Phase A: q-norm + mem branch; mask-skipped, nt-tagged mem_kv stream ----
    {
        const int i16 = lane & 15;        // d-quarter
        const int kv  = (lane >> 4) & 1;  // 0 = k-part, 1 = v-part
        const int h2  = lane >> 5;        // j parity

        // hoist all 8 rows' mem_mask ballots + q scalars (breaks per-row latency chain)
        unsigned int mbs[8];
        float qv8[8];
        #pragma unroll
        for (int r = 0; r < 8; r++) {
            const int ig = i0 + w * 8 + r;
            qv8[r] = q[((size_t)bh * SEQ + ig) * DIM + lane];
        }
        #pragma unroll
        for (int r = 0; r < 8; r++) {
            const int ig = i0 + w * 8 + r;
            size_t mmrow = ((size_t)bh * SEQ + ig) * KNN;
            bool mybit = mask_is_int ? (((const int*)mem_mask)[mmrow + (lane & 31)] != 0)
                                     : (((const unsigned char*)mem_mask)[mmrow + (lane & 31)] != 0);
            mbs[r] = (unsigned int)__ballot(mybit);   // bits 0..31 = j
        }

        for (int r = 0; r < 8; r++) {
            const int il = w * 8 + r;
            const int ig = i0 + il;
            // q l2-norm
            float qv = qv8[r];
            float ssq = qv * qv;
            #pragma unroll
            for (int m2 = 1; m2 < 64; m2 <<= 1) ssq += __shfl_xor(ssq, m2);
            float qn = qv / fmaxf(sqrtf(ssq), 1e-12f);
            qn_s[il][lane] = qn;
            const unsigned int mb = mbs[r];
            // 16 contiguous 1KB wave loads, PREDICATED on mask bit (skip masked j's 512B)
            const float* rowp = mem_kv + ((size_t)bh * SEQ + ig) * (KNN * 2 * DIM);
            F4 dat[16];
            #pragma unroll
            for (int t = 0; t < 16; t++) {
                const int j = 2 * t + h2;
                dat[t].e = 0.f;
                if ((mb >> j) & 1u)
                    dat[t].e = __builtin_nontemporal_load((const f32x4*)(rowp + (size_t)(t * 64 + lane) * 4));
            }
            F4 qd; qd.v = *(const float4*)&qn_s[il][i16 * 4];
            // k-dots (valid in k-lanes): s_j for j = 2t + h2
            float pj[16];
            #pragma unroll
            for (int t = 0; t < 16; t++) {
                float part = dat[t].f[0] * qd.f[0] + dat[t].f[1] * qd.f[1]
                           + dat[t].f[2] * qd.f[2] + dat[t].f[3] * qd.f[3];
                part += __shfl_xor(part, 1);
                part += __shfl_xor(part, 2);
                part += __shfl_xor(part, 4);
                part += __shfl_xor(part, 8);
                float s = part * scale;
                const int j = 2 * t + h2;
                if (!((mb >> j) & 1u)) s = NEGF;
                pj[t] = s;
            }
            // row max over 32 j (combine parities via xor 32)
            float mx = pj[0];
            #pragma unroll
            for (int t = 1; t < 16; t++) mx = fmaxf(mx, pj[t]);
            mx = fmaxf(mx, __shfl_xor(mx, 32));
            // p = exp(s - mx), row sum
            float ls = 0.f;
            #pragma unroll
            for (int t = 0; t < 16; t++) {
                float p = __expf(pj[t] - mx);
                pj[t] = p;
                ls += p;
            }
            ls += __shfl_xor(ls, 32);
            // weighted V (valid in v-lanes): p from partner k-lane via xor 16
            float a0 = 0.f, a1 = 0.f, a2 = 0.f, a3 = 0.f;
            #pragma unroll
            for (int t = 0; t < 16; t++) {
                float p = __shfl_xor(pj[t], 16);
                a0 += p * dat[t].f[0];
                a1 += p * dat[t].f[1];
                a2 += p * dat[t].f[2];
                a3 += p * dat[t].f[3];
            }
            a0 += __shfl_xor(a0, 32);
            a1 += __shfl_xor(a1, 32);
            a2 += __shfl_xor(a2, 32);
            a3 += __shfl_xor(a3, 32);
            if (kv == 1 && h2 == 0) {
                F4 o; o.f[0] = a0; o.f[1] = a1; o.f[2] = a2; o.f[3] = a3;
                *(float4*)&maccs[il][i16 * 4] = o.v;
            }
            if (lane == 0) { mmem_s[il] = mx; lmem_s[il] = ls; }
        }
    }
    __syncthreads();

    // ---------------- Q A-fragments (registers, bf16) ----------------
    bf16x8 qa[2][2];
    #pragma unroll
    for (int mt = 0; mt < 2; mt++)
        #pragma unroll
        for (int kc = 0; kc < 2; kc++) {
            const float* qp = &qn_s[mt * 16 + c][kc * 32 + g * 8];
            F4 a0, a1; a0.v = *(const float4*)qp; a1.v = *(const float4*)(qp + 4);
            S8 t;
            #pragma unroll
            for (int e = 0; e < 4; e++) { t.us[e] = f2bf(a0.f[e]); t.us[4 + e] = f2bf(a1.f[e]); }
            qa[mt][kc] = t.b;
        }

    // ---------------- Flash over key tiles (waves split jt) ----------------
    f32x4 oacc[4][2];
    #pragma unroll
    for (int mtd = 0; mtd < 4; mtd++)
        #pragma unroll
        for (int ni = 0; ni < 2; ni++)
            #pragma unroll
            for (int r = 0; r < 4; r++) oacc[mtd][ni][r] = 0.f;
    float mrow[2][4], lrow[2][4];
    #pragma unroll
    for (int mt = 0; mt < 2; mt++)
        #pragma unroll
        for (int r = 0; r < 4; r++) { mrow[mt][r] = NEGF; lrow[mt][r] = 0.f; }

    const int nkt = ((i0 + QT - 1) >> 6) + 1;
    const unsigned short* knBb = knB + (size_t)b * SEQ * DIM;
    const unsigned short* vTb  = vT  + (size_t)b * DIM * SEQ;

    for (int jt = w; jt < nkt; jt += 4) {
        const int jb = jt * KT;

        bf16x8 va[4][2];
        #pragma unroll
        for (int mtd = 0; mtd < 4; mtd++)
            #pragma unroll
            for (int kk2 = 0; kk2 < 2; kk2++) {
                const unsigned short* vp = vTb + (size_t)(mtd * 16 + c) * SEQ + jb + kk2 * 32 + 4 * g;
                S8 t; t.u2[0] = *(const uint2*)vp; t.u2[1] = *(const uint2*)(vp + 16);
                va[mtd][kk2] = t.b;
            }

        f32x4 sacc[2][4];
        #pragma unroll
        for (int mt = 0; mt < 2; mt++)
            #pragma unroll
            for (int nt = 0; nt < 4; nt++)
                #pragma unroll
                for (int r = 0; r < 4; r++) sacc[mt][nt][r] = 0.f;
        #pragma unroll
        for (int kc = 0; kc < 2; kc++) {
            #pragma unroll
            for (int nt = 0; nt < 4; nt++) {
                S8 kb; kb.u4 = *(const uint4*)(knBb + (size_t)(jb + nt * 16 + c) * DIM + kc * 32 + g * 8);
                #pragma unroll
                for (int mt = 0; mt < 2; mt++)
                    sacc[mt][nt] = __builtin_amdgcn_mfma_f32_16x16x32_bf16(qa[mt][kc], kb.b, sacc[mt][nt], 0, 0, 0);
            }
        }

        float mv4[4];
        #pragma unroll
        for (int nt = 0; nt < 4; nt++) mv4[nt] = mask[b * SEQ + jb + nt * 16 + c];
        const bool docausal = (jb + 63 > i0);
        float corr[2][4];
        #pragma unroll
        for (int mt = 0; mt < 2; mt++) {
            #pragma unroll
            for (int nt = 0; nt < 4; nt++)
                #pragma unroll
                for (int r = 0; r < 4; r++) {
                    float s = sacc[mt][nt][r] * scale + NEGF * (1.f - mv4[nt]);
                    if (docausal) {
                        int j = jb + nt * 16 + c;
                        int i = i0 + mt * 16 + 4 * g + r;
                        if (j > i) s = NEGF;
                    }
                    sacc[mt][nt][r] = s;
                }
            #pragma unroll
            for (int r = 0; r < 4; r++) {
                float rmax = fmaxf(fmaxf(sacc[mt][0][r], sacc[mt][1][r]),
                                   fmaxf(sacc[mt][2][r], sacc[mt][3][r]));
                #pragma unroll
                for (int m2 = 1; m2 < 16; m2 <<= 1) rmax = fmaxf(rmax, __shfl_xor(rmax, m2));
                float mnew = fmaxf(mrow[mt][r], rmax);
                corr[mt][r] = __expf(mrow[mt][r] - mnew);
                mrow[mt][r] = mnew;
            }
        }

        #pragma unroll
        for (int mt = 0; mt < 2; mt++) {
            float psum[4] = {0.f, 0.f, 0.f, 0.f};
            #pragma unroll
            for (int nt = 0; nt < 4; nt++)
                #pragma unroll
                for (int r = 0; r < 4; r++) {
                    float p = __expf(sacc[mt][nt][r] - mrow[mt][r]);
                    psum[r] += p;
                    fragbuf[w][mt][nt >> 1][c >> 2][4 * g + r][(c & 3) + 4 * (nt & 1)] = f2bf(p);
                }
            #pragma unroll
            for (int r = 0; r < 4; r++) {
                float ps = psum[r];
                #pragma unroll
                for (int m2 = 1; m2 < 16; m2 <<= 1) ps += __shfl_xor(ps, m2);
                lrow[mt][r] = lrow[mt][r] * corr[mt][r] + ps;
            }
        }

        if (c == 0) {
            #pragma unroll
            for (int mt = 0; mt < 2; mt++)
                #pragma unroll
                for (int r = 0; r < 4; r++)
                    corr_s[w][mt * 16 + 4 * g + r] = corr[mt][r];
        }
        float cf0 = corr_s[w][c];
        float cf1 = corr_s[w][16 + c];
        #pragma unroll
        for (int mtd = 0; mtd < 4; mtd++)
            #pragma unroll
            for (int r = 0; r < 4; r++) { oacc[mtd][0][r] *= cf0; oacc[mtd][1][r] *= cf1; }

        #pragma unroll
        for (int kk2 = 0; kk2 < 2; kk2++)
            #pragma unroll
            for (int ni = 0; ni < 2; ni++) {
                S8 pb; pb.u4 = *(const uint4*)&fragbuf[w][ni][kk2][g][c][0];
                #pragma unroll
                for (int mtd = 0; mtd < 4; mtd++)
                    oacc[mtd][ni] = __builtin_amdgcn_mfma_f32_16x16x32_bf16(va[mtd][kk2], pb.b, oacc[mtd][ni], 0, 0, 0);
            }
    }

    // ---------------- merge: 4 wave-partials + mem branch ----------------
    if (c == 0) {
        #pragma unroll
        for (int mt = 0; mt < 2; mt++)
            #pragma unroll
            for (int r = 0; r < 4; r++) {
                mlw[w][0][mt * 16 + 4 * g + r] = mrow[mt][r];
                mlw[w][1][mt * 16 + 4 * g + r] = lrow[mt][r];
            }
    }
    __syncthreads();
    {
        int i = tid >> 3;
        int d0 = (tid & 7) * 8;
        float mM = mmem_s[i];
        #pragma unroll
        for (int w2 = 0; w2 < 4; w2++) mM = fmaxf(mM, mlw[w2][0][i]);
        float em = __expf(mmem_s[i] - mM);
        float L = lmem_s[i] * em;
        #pragma unroll
        for (int w2 = 0; w2 < 4; w2++) L += mlw[w2][1][i] * __expf(mlw[w2][0][i] - mM);
        #pragma unroll
        for (int e = 0; e < 8; e++) maccs[i][d0 + e] *= em;
        if ((tid & 7) == 0) linv_s[i] = 1.f / L;
        if ((tid & 7) == 1) corr_s[0][i] = mM;   // stash global max
    }
    __syncthreads();
    float ew0 = __expf(mlw[w][0][c]      - corr_s[0][c]);
    float ew1 = __expf(mlw[w][0][16 + c] - corr_s[0][16 + c]);
    for (int w2 = 0; w2 < 4; w2++) {
        if (w == w2) {
            #pragma unroll
            for (int mtd = 0; mtd < 4; mtd++)
                #pragma unroll
                for (int r = 0; r < 4; r++) {
                    maccs[c][mtd * 16 + 4 * g + r]      += oacc[mtd][0][r] * ew0;
                    maccs[16 + c][mtd * 16 + 4 * g + r] += oacc[mtd][1][r] * ew1;
                }
        }
        __syncthreads();
    }
    {
        int i = tid >> 3;
        int d0 = (tid & 7) * 8;
        float inv = linv_s[i];
        F4 o0, o1;
        o0.v = *(const float4*)&maccs[i][d0];
        o1.v = *(const float4*)&maccs[i][d0 + 4];
        #pragma unroll
        for (int e = 0; e < 4; e++) { o0.f[e] *= inv; o1.f[e] *= inv; }
        float* op = out + ((size_t)bh * SEQ + i0 + i) * DIM + d0;
        *(float4*)op = o0.v;
        *(float4*)(op + 4) = o1.v;
    }
}

extern "C" void kernel_launch(void* const* d_in, const int* in_sizes, int n_in,
                              void* d_out, int out_size, void* d_ws, size_t ws_size,
                              hipStream_t stream) {
    const float* q           = (const float*)d_in[0];
    const float* k           = (const float*)d_in[1];
    const float* v           = (const float*)d_in[2];
    const float* scale_param = (const float*)d_in[3];
    const float* mem_kv      = (const float*)d_in[4];
    const float* mask        = (const float*)d_in[5];
    const void*  mem_mask    = d_in[6];
    float* out = (float*)d_out;

    int* flag = (int*)d_ws;
    unsigned short* knB = (unsigned short*)((char*)d_ws + 256);
    unsigned short* vT  = (unsigned short*)((char*)d_ws + 256 + (size_t)BATCH * SEQ * DIM * 2);

    prep_kernel<<<dim3(BATCH * SEQ / 64), dim3(256), 0, stream>>>(
        k, v, (const unsigned char*)mem_mask, knB, vT, flag);
    attn_kernel<<<dim3(BATCH * HEADS * (SEQ / QT)), dim3(256), 0, stream>>>(
        q, scale_param, mem_kv, mask, mem_mask, knB, vT, flag, out);
}

// Round 6
// 165.128 us; speedup vs baseline: 2.4946x; 1.0416x over previous
//
#include <hip/hip_runtime.h>
#include <float.h>

#define HEADS 8
#define DIM 64
#define BATCH 2
#define SEQ 2048
#define KNN 32
#define QT 32
#define KT 64
#define NEGF (-3.402823466e38f)

typedef float f32x4 __attribute__((ext_vector_type(4)));
typedef __bf16 bf16x8 __attribute__((ext_vector_type(8)));

union F4 { float4 v; f32x4 e; float f[4]; };
union S8 { bf16x8 b; unsigned int u[4]; unsigned short us[8]; uint4 u4; uint2 u2[2]; };

__device__ __forceinline__ unsigned short f2bf(float x) {
    unsigned int u = __float_as_uint(x);
    u = (u + 0x7fffu + ((u >> 16) & 1u)) >> 16;
    return (unsigned short)u;
}

// ws layout (bytes):
//   flag  @ 0
//   knB   @ 1024            bf16 (B,S,D)        512 KB
//   vT    @ 1024 + 512K     bf16 (B,D,S)        512 KB
//   qnB   @ 1024 + 1M       bf16 (B,H,S,D)      4 MB
//   maccG @ 1024 + 5M       f32  (B,H,S,D)      8 MB
//   mG    @ 1024 + 13M      f32  (B,H,S)        128 KB
//   lG    @ 1024 + 13M+256K f32  (B,H,S)        128 KB

__global__ __launch_bounds__(256) void prep_kernel(const float* __restrict__ k,
                                                   const float* __restrict__ v,
                                                   const unsigned char* __restrict__ mmraw,
                                                   unsigned short* __restrict__ knB,
                                                   unsigned short* __restrict__ vT,
                                                   int* __restrict__ flag) {
    __shared__ float vt_s[64][65];
    const int w = threadIdx.x >> 6, lane = threadIdx.x & 63;
    const int s0 = blockIdx.x * 64;       // global row index b*SEQ+s
    const int b = s0 >> 11;
    for (int rr = 0; rr < 16; rr++) {
        const int sl = w * 16 + rr;
        const int row = s0 + sl;
        float kv = k[(size_t)row * DIM + lane];
        float ssq = kv * kv;
        #pragma unroll
        for (int m = 1; m < 64; m <<= 1) ssq += __shfl_xor(ssq, m);
        float kn = kv / fmaxf(sqrtf(ssq), 1e-12f);
        knB[(size_t)row * DIM + lane] = f2bf(kn);
        vt_s[sl][lane] = v[(size_t)row * DIM + lane];
    }
    __syncthreads();
    {   // transposed V write: thread -> (d, 16-s chunk), 32B contiguous stores
        const int d = threadIdx.x >> 2;
        const int sc = (threadIdx.x & 3) * 16;
        const int s_base = s0 & 2047;
        unsigned short tmp[16];
        #pragma unroll
        for (int e = 0; e < 16; e++) tmp[e] = f2bf(vt_s[sc + e][d]);
        unsigned short* dst = vT + ((size_t)b * DIM + d) * SEQ + s_base + sc;
        *(uint4*)dst = *(uint4*)&tmp[0];
        *(uint4*)(dst + 8) = *(uint4*)&tmp[8];
    }
    if (blockIdx.x == 0 && w == 0) {
        int bad = 0;
        #pragma unroll
        for (int t = 0; t < 8; t++) {
            int idx = t * 64 + lane;
            if ((idx & 3) != 0 && mmraw[idx] != 0) bad = 1;
        }
        unsigned long long anybad = __ballot(bad);
        if (lane == 0) flag[0] = (anybad == 0ULL) ? 1 : 0;
    }
}

// High-occupancy mem-branch streamer: 4 waves/block, 4 rows/wave, no LDS.
__global__ __launch_bounds__(256) void mem_kernel(
    const float* __restrict__ q,           // B,H,S,D
    const float* __restrict__ scale_param, // H
    const float* __restrict__ mem_kv,      // B,H,S,KNN,2,D
    const void*  __restrict__ mem_mask,    // B,H,S,KNN
    const int*   __restrict__ flagp,
    unsigned short* __restrict__ qnB,      // out: bf16 normalized q
    float* __restrict__ maccG,             // out: (B,H,S,D) weighted mem_v (unnormalized)
    float* __restrict__ mG,                // out: (B,H,S) row max
    float* __restrict__ lG)                // out: (B,H,S) row sum
{
    const int w = threadIdx.x >> 6, lane = threadIdx.x & 63;
    const int i16 = lane & 15;        // d-quarter
    const int kv  = (lane >> 4) & 1;  // 0 = k-part, 1 = v-part
    const int h2  = lane >> 5;        // j parity
    const int mask_is_int = flagp[0];
    const int gid0 = blockIdx.x * 16 + w * 4;       // 16 rows/block, same bh
    const int bh = gid0 >> 11;
    const float scale = __expf(scale_param[bh & 7]);

    for (int r = 0; r < 4; r++) {
        const int gid = gid0 + r;
        // q l2-norm (fp32 exact)
        float qv = q[(size_t)gid * DIM + lane];
        float ssq = qv * qv;
        #pragma unroll
        for (int m2 = 1; m2 < 64; m2 <<= 1) ssq += __shfl_xor(ssq, m2);
        float qn = qv / fmaxf(sqrtf(ssq), 1e-12f);
        qnB[(size_t)gid * DIM + lane] = f2bf(qn);
        F4 qd;
        #pragma unroll
        for (int e = 0; e < 4; e++) qd.f[e] = __shfl(qn, i16 * 4 + e);
        // mem_mask ballot (bits 0..31 = j)
        size_t mmrow = (size_t)gid * KNN;
        bool mybit = mask_is_int ? (((const int*)mem_mask)[mmrow + (lane & 31)] != 0)
                                 : (((const unsigned char*)mem_mask)[mmrow + (lane & 31)] != 0);
        const unsigned int mb = (unsigned int)__ballot(mybit);
        // 16 contiguous 1KB wave loads, predicated on mask bit (skip masked j's 512B)
        const float* rowp = mem_kv + (size_t)gid * (KNN * 2 * DIM);
        F4 dat[16];
        #pragma unroll
        for (int t = 0; t < 16; t++) {
            const int j = 2 * t + h2;
            dat[t].e = 0.f;
            if ((mb >> j) & 1u)
                dat[t].e = __builtin_nontemporal_load((const f32x4*)(rowp + (size_t)(t * 64 + lane) * 4));
        }
        // k-dots (valid in k-lanes): s_j for j = 2t + h2
        float pj[16];
        #pragma unroll
        for (int t = 0; t < 16; t++) {
            float part = dat[t].f[0] * qd.f[0] + dat[t].f[1] * qd.f[1]
                       + dat[t].f[2] * qd.f[2] + dat[t].f[3] * qd.f[3];
            part += __shfl_xor(part, 1);
            part += __shfl_xor(part, 2);
            part += __shfl_xor(part, 4);
            part += __shfl_xor(part, 8);
            float s = part * scale;
            const int j = 2 * t + h2;
            if (!((mb >> j) & 1u)) s = NEGF;
            pj[t] = s;
        }
        float mx = pj[0];
        #pragma unroll
        for (int t = 1; t < 16; t++) mx = fmaxf(mx, pj[t]);
        mx = fmaxf(mx, __shfl_xor(mx, 32));
        float ls = 0.f;
        #pragma unroll
        for (int t = 0; t < 16; t++) {
            float p = __expf(pj[t] - mx);
            pj[t] = p;
            ls += p;
        }
        ls += __shfl_xor(ls, 32);
        // weighted V (valid in v-lanes): p from partner k-lane via xor 16
        float a0 = 0.f, a1 = 0.f, a2 = 0.f, a3 = 0.f;
        #pragma unroll
        for (int t = 0; t < 16; t++) {
            float p = __shfl_xor(pj[t], 16);
            a0 += p * dat[t].f[0];
            a1 += p * dat[t].f[1];
            a2 += p * dat[t].f[2];
            a3 += p * dat[t].f[3];
        }
        a0 += __shfl_xor(a0, 32);
        a1 += __shfl_xor(a1, 32);
        a2 += __shfl_xor(a2, 32);
        a3 += __shfl_xor(a3, 32);
        if (kv == 1 && h2 == 0) {
            F4 o; o.f[0] = a0; o.f[1] = a1; o.f[2] = a2; o.f[3] = a3;
            *(float4*)(maccG + (size_t)gid * DIM + i16 * 4) = o.v;
        }
        if (lane == 0) { mG[gid] = mx; lG[gid] = ls; }
    }
}

__global__ __launch_bounds__(256) void flash_kernel(
    const float* __restrict__ scale_param,  // H
    const float* __restrict__ mask,         // B,S float
    const unsigned short* __restrict__ knB, // B,S,D bf16 (l2-normed k)
    const unsigned short* __restrict__ vT,  // B,D,S bf16
    const unsigned short* __restrict__ qnB, // B,H,S,D bf16 (l2-normed q)
    const float* __restrict__ maccG,        // B,H,S,D mem-branch acc
    const float* __restrict__ mG,           // B,H,S
    const float* __restrict__ lG,           // B,H,S
    float* __restrict__ out)                // B,H,S,D
{
    __shared__ float maccs[QT][DIM + 4];
    __shared__ float mmem_s[QT], lmem_s[QT];
    __shared__ unsigned short fragbuf[4][2][2][4][16][8]; // per-wave P in B-frag layout
    __shared__ float corr_s[4][QT];
    __shared__ float mlw[4][2][QT];
    __shared__ float linv_s[QT];

    const int tid = threadIdx.x;
    const int w = tid >> 6;
    const int lane = tid & 63;
    const int g = lane >> 4;
    const int c = lane & 15;
    const int bid = blockIdx.x;
    const int qt = 63 - (bid & 63);       // heavy tiles first
    const int bh = bid >> 6;
    const int b = bh >> 3;
    const int h = bh & 7;
    const int i0 = qt * QT;

    const float scale = __expf(scale_param[h]);

    // ---- load mem-branch partials into LDS; q A-frags from qnB ----
    {
        int i = tid >> 3, d0 = (tid & 7) * 8;
        const float* src = maccG + ((size_t)bh * SEQ + i0 + i) * DIM + d0;
        *(float4*)&maccs[i][d0]     = *(const float4*)src;
        *(float4*)&maccs[i][d0 + 4] = *(const float4*)(src + 4);
        if (tid < QT) {
            mmem_s[tid] = mG[(size_t)bh * SEQ + i0 + tid];
            lmem_s[tid] = lG[(size_t)bh * SEQ + i0 + tid];
        }
    }
    bf16x8 qa[2][2];
    #pragma unroll
    for (int mt = 0; mt < 2; mt++)
        #pragma unroll
        for (int kc = 0; kc < 2; kc++) {
            S8 t;
            t.u4 = *(const uint4*)(qnB + ((size_t)bh * SEQ + i0 + mt * 16 + c) * DIM + kc * 32 + g * 8);
            qa[mt][kc] = t.b;
        }

    // ---------------- Flash over key tiles (waves split jt) ----------------
    f32x4 oacc[4][2];
    #pragma unroll
    for (int mtd = 0; mtd < 4; mtd++)
        #pragma unroll
        for (int ni = 0; ni < 2; ni++)
            #pragma unroll
            for (int r = 0; r < 4; r++) oacc[mtd][ni][r] = 0.f;
    float mrow[2][4], lrow[2][4];
    #pragma unroll
    for (int mt = 0; mt < 2; mt++)
        #pragma unroll
        for (int r = 0; r < 4; r++) { mrow[mt][r] = NEGF; lrow[mt][r] = 0.f; }

    const int nkt = ((i0 + QT - 1) >> 6) + 1;
    const unsigned short* knBb = knB + (size_t)b * SEQ * DIM;
    const unsigned short* vTb  = vT  + (size_t)b * DIM * SEQ;

    for (int jt = w; jt < nkt; jt += 4) {
        const int jb = jt * KT;

        bf16x8 va[4][2];
        #pragma unroll
        for (int mtd = 0; mtd < 4; mtd++)
            #pragma unroll
            for (int kk2 = 0; kk2 < 2; kk2++) {
                const unsigned short* vp = vTb + (size_t)(mtd * 16 + c) * SEQ + jb + kk2 * 32 + 4 * g;
                S8 t; t.u2[0] = *(const uint2*)vp; t.u2[1] = *(const uint2*)(vp + 16);
                va[mtd][kk2] = t.b;
            }

        f32x4 sacc[2][4];
        #pragma unroll
        for (int mt = 0; mt < 2; mt++)
            #pragma unroll
            for (int nt = 0; nt < 4; nt++)
                #pragma unroll
                for (int r = 0; r < 4; r++) sacc[mt][nt][r] = 0.f;
        #pragma unroll
        for (int kc = 0; kc < 2; kc++) {
            #pragma unroll
            for (int nt = 0; nt < 4; nt++) {
                S8 kb; kb.u4 = *(const uint4*)(knBb + (size_t)(jb + nt * 16 + c) * DIM + kc * 32 + g * 8);
                #pragma unroll
                for (int mt = 0; mt < 2; mt++)
                    sacc[mt][nt] = __builtin_amdgcn_mfma_f32_16x16x32_bf16(qa[mt][kc], kb.b, sacc[mt][nt], 0, 0, 0);
            }
        }

        float mv4[4];
        #pragma unroll
        for (int nt = 0; nt < 4; nt++) mv4[nt] = mask[b * SEQ + jb + nt * 16 + c];
        const bool docausal = (jb + 63 > i0);
        float corr[2][4];
        #pragma unroll
        for (int mt = 0; mt < 2; mt++) {
            #pragma unroll
            for (int nt = 0; nt < 4; nt++)
                #pragma unroll
                for (int r = 0; r < 4; r++) {
                    float s = sacc[mt][nt][r] * scale + NEGF * (1.f - mv4[nt]);
                    if (docausal) {
                        int j = jb + nt * 16 + c;
                        int i = i0 + mt * 16 + 4 * g + r;
                        if (j > i) s = NEGF;
                    }
                    sacc[mt][nt][r] = s;
                }
            #pragma unroll
            for (int r = 0; r < 4; r++) {
                float rmax = fmaxf(fmaxf(sacc[mt][0][r], sacc[mt][1][r]),
                                   fmaxf(sacc[mt][2][r], sacc[mt][3][r]));
                #pragma unroll
                for (int m2 = 1; m2 < 16; m2 <<= 1) rmax = fmaxf(rmax, __shfl_xor(rmax, m2));
                float mnew = fmaxf(mrow[mt][r], rmax);
                corr[mt][r] = __expf(mrow[mt][r] - mnew);
                mrow[mt][r] = mnew;
            }
        }

        #pragma unroll
        for (int mt = 0; mt < 2; mt++) {
            float psum[4] = {0.f, 0.f, 0.f, 0.f};
            #pragma unroll
            for (int nt = 0; nt < 4; nt++)
                #pragma unroll
                for (int r = 0; r < 4; r++) {
                    float p = __expf(sacc[mt][nt][r] - mrow[mt][r]);
                    psum[r] += p;
                    fragbuf[w][mt][nt >> 1][c >> 2][4 * g + r][(c & 3) + 4 * (nt & 1)] = f2bf(p);
                }
            #pragma unroll
            for (int r = 0; r < 4; r++) {
                float ps = psum[r];
                #pragma unroll
                for (int m2 = 1; m2 < 16; m2 <<= 1) ps += __shfl_xor(ps, m2);
                lrow[mt][r] = lrow[mt][r] * corr[mt][r] + ps;
            }
        }

        if (c == 0) {
            #pragma unroll
            for (int mt = 0; mt < 2; mt++)
                #pragma unroll
                for (int r = 0; r < 4; r++)
                    corr_s[w][mt * 16 + 4 * g + r] = corr[mt][r];
        }
        float cf0 = corr_s[w][c];
        float cf1 = corr_s[w][16 + c];
        #pragma unroll
        for (int mtd = 0; mtd < 4; mtd++)
            #pragma unroll
            for (int r = 0; r < 4; r++) { oacc[mtd][0][r] *= cf0; oacc[mtd][1][r] *= cf1; }

        #pragma unroll
        for (int kk2 = 0; kk2 < 2; kk2++)
            #pragma unroll
            for (int ni = 0; ni < 2; ni++) {
                S8 pb; pb.u4 = *(const uint4*)&fragbuf[w][ni][kk2][g][c][0];
                #pragma unroll
                for (int mtd = 0; mtd < 4; mtd++)
                    oacc[mtd][ni] = __builtin_amdgcn_mfma_f32_16x16x32_bf16(va[mtd][kk2], pb.b, oacc[mtd][ni], 0, 0, 0);
            }
    }

    // ---------------- merge: 4 wave-partials + mem branch ----------------
    if (c == 0) {
        #pragma unroll
        for (int mt = 0; mt < 2; mt++)
            #pragma unroll
            for (int r = 0; r < 4; r++) {
                mlw[w][0][mt * 16 + 4 * g + r] = mrow[mt][r];
                mlw[w][1][mt * 16 + 4 * g + r] = lrow[mt][r];
            }
    }
    __syncthreads();
    {
        int i = tid >> 3;
        int d0 = (tid & 7) * 8;
        float mM = mmem_s[i];
        #pragma unroll
        for (int w2 = 0; w2 < 4; w2++) mM = fmaxf(mM, mlw[w2][0][i]);
        float em = __expf(mmem_s[i] - mM);
        float L = lmem_s[i] * em;
        #pragma unroll
        for (int w2 = 0; w2 < 4; w2++) L += mlw[w2][1][i] * __expf(mlw[w2][0][i] - mM);
        #pragma unroll
        for (int e = 0; e < 8; e++) maccs[i][d0 + e] *= em;
        if ((tid & 7) == 0) linv_s[i] = 1.f / L;
        if ((tid & 7) == 1) corr_s[0][i] = mM;   // stash global max
    }
    __syncthreads();
    float ew0 = __expf(mlw[w][0][c]      - corr_s[0][c]);
    float ew1 = __expf(mlw[w][0][16 + c] - corr_s[0][16 + c]);
    for (int w2 = 0; w2 < 4; w2++) {
        if (w == w2) {
            #pragma unroll
            for (int mtd = 0; mtd < 4; mtd++)
                #pragma unroll
                for (int r = 0; r < 4; r++) {
                    maccs[c][mtd * 16 + 4 * g + r]      += oacc[mtd][0][r] * ew0;
                    maccs[16 + c][mtd * 16 + 4 * g + r] += oacc[mtd][1][r] * ew1;
                }
        }
        __syncthreads();
    }
    {
        int i = tid >> 3;
        int d0 = (tid & 7) * 8;
        float inv = linv_s[i];
        F4 o0, o1;
        o0.v = *(const float4*)&maccs[i][d0];
        o1.v = *(const float4*)&maccs[i][d0 + 4];
        #pragma unroll
        for (int e = 0; e < 4; e++) { o0.f[e] *= inv; o1.f[e] *= inv; }
        float* op = out + ((size_t)bh * SEQ + i0 + i) * DIM + d0;
        *(float4*)op = o0.v;
        *(float4*)(op + 4) = o1.v;
    }
}

extern "C" void kernel_launch(void* const* d_in, const int* in_sizes, int n_in,
                              void* d_out, int out_size, void* d_ws, size_t ws_size,
                              hipStream_t stream) {
    const float* q           = (const float*)d_in[0];
    const float* k           = (const float*)d_in[1];
    const float* v           = (const float*)d_in[2];
    const float* scale_param = (const float*)d_in[3];
    const float* mem_kv      = (const float*)d_in[4];
    const float* mask        = (const float*)d_in[5];
    const void*  mem_mask    = d_in[6];
    float* out = (float*)d_out;

    char* base = (char*)d_ws;
    int* flag           = (int*)base;
    unsigned short* knB = (unsigned short*)(base + 1024);
    unsigned short* vT  = (unsigned short*)(base + 1024 + (512ull << 10));
    unsigned short* qnB = (unsigned short*)(base + 1024 + (1ull << 20));
    float* maccG        = (float*)(base + 1024 + (5ull << 20));
    float* mG           = (float*)(base + 1024 + (13ull << 20));
    float* lG           = (float*)(base + 1024 + (13ull << 20) + (256ull << 10));

    prep_kernel<<<dim3(BATCH * SEQ / 64), dim3(256), 0, stream>>>(
        k, v, (const unsigned char*)mem_mask, knB, vT, flag);
    mem_kernel<<<dim3(BATCH * HEADS * SEQ / 16), dim3(256), 0, stream>>>(
        q, scale_param, mem_kv, mem_mask, flag, qnB, maccG, mG, lG);
    flash_kernel<<<dim3(BATCH * HEADS * (SEQ / QT)), dim3(256), 0, stream>>>(
        scale_param, mask, knB, vT, qnB, maccG, mG, lG, out);
}